// Round 1
// baseline (78.029 us; speedup 1.0000x reference)
//
#include <hip/hip_runtime.h>

#define W 1280
#define H 384
#define ND 21   // MAXDISP

// One block per (batch, row). Stage 3-row column sums (with +/-22
// edge-replicated pads) in LDS, then each thread computes 5 strided
// columns: min over 21 disparities of |(C[c]+C[c+dir])/6 - C[c+dir*(i+2)]/3 + (i+1)|.
// dir=+1 reproduces maskl (bs<0); dir=-1 reproduces the flipped maskr (bs>0);
// bs==0 writes zeros.
__global__ __launch_bounds__(256) void occl_kernel(const float* __restrict__ disp,
                                                   const float* __restrict__ bsl,
                                                   float* __restrict__ out) {
    const int row   = blockIdx.x % H;
    const int batch = blockIdx.x / H;
    const float bs  = bsl[batch];
    float* __restrict__ orow = out + (size_t)(batch * H + row) * W;

    if (bs == 0.0f) {
        for (int c = threadIdx.x; c < W; c += 256) orow[c] = 0.0f;
        return;
    }
    const int dir = (bs < 0.0f) ? 1 : -1;

    __shared__ float Cbuf[W + 48];
    float* Cs = Cbuf + 24;   // valid indices -22 .. W+21

    const float* __restrict__ dbase = disp + (size_t)batch * H * W;
    const float* __restrict__ r0 = dbase + (size_t)max(row - 1, 0) * W;
    const float* __restrict__ r1 = dbase + (size_t)row * W;
    const float* __restrict__ r2 = dbase + (size_t)min(row + 1, H - 1) * W;

    for (int c = threadIdx.x; c < W; c += 256) {
        Cs[c] = r0[c] + r1[c] + r2[c];
    }
    // Edge-replicated pads (redundant loads hit L1).
    const int t = threadIdx.x;
    if (t < 22) {
        float cl = r0[0] + r1[0] + r2[0];
        Cs[-1 - t] = cl;                       // Cs[-22..-1]
    } else if (t >= 64 && t < 86) {
        float cr = r0[W - 1] + r1[W - 1] + r2[W - 1];
        Cs[W + (t - 64)] = cr;                 // Cs[W..W+21]
    }
    __syncthreads();

    for (int c = threadIdx.x; c < W; c += 256) {
        const float base = (1.0f / 6.0f) * (Cs[c] + Cs[c + dir]);
        int idx = c + 2 * dir;
        float m = 1e30f;
        #pragma unroll
        for (int i = 0; i < ND; i++) {
            float v = fabsf(base - (1.0f / 3.0f) * Cs[idx] + (float)(i + 1));
            m = fminf(m, v);
            idx += dir;
        }
        orow[c] = fminf(m, 1.0f);   // m >= 0 already (abs), so clip(0,1) == min(.,1)
    }
}

extern "C" void kernel_launch(void* const* d_in, const int* in_sizes, int n_in,
                              void* d_out, int out_size, void* d_ws, size_t ws_size,
                              hipStream_t stream) {
    const float* disp = (const float*)d_in[0];
    const float* bsl  = (const float*)d_in[1];
    float* out        = (float*)d_out;
    const int n_batch = in_sizes[1];   // bsline has one entry per batch

    dim3 grid(n_batch * H);
    occl_kernel<<<grid, 256, 0, stream>>>(disp, bsl, out);
}

// Round 2
// 75.373 us; speedup vs baseline: 1.0352x; 1.0352x over previous
//
#include <hip/hip_runtime.h>

#define W  1280
#define H  384
#define ND 21     // MAXDISP
#define BT 320    // threads per block: 4 columns per thread

// Per output column c (dir=+1, i.e. maskl):
//   base = (C[c] + C[c+1]) / 6
//   mask = clip( min_i |base + (i+1) - C[c+2+i]/3| , 0, 1)
// where C = 3-row column sum (rows edge-clamped, columns edge-clamped right).
// dir=-1 is the algebraic collapse of flip(mask(flip(d))) — mirrored offsets.

template <int DIR>
__device__ __forceinline__ void compute4(const float* __restrict__ Cs,
                                         float* __restrict__ orow, int t) {
    // 28 contiguous colsums into registers: covers cols 4t..4t+3 and all
    // 21 disparity taps in direction DIR.
    float V[28];
    const float4* p = (const float4*)(Cs + ((DIR > 0) ? 4 * t : 4 * t - 24));
    #pragma unroll
    for (int m = 0; m < 7; m++) {
        float4 f = p[m];
        V[4 * m + 0] = f.x; V[4 * m + 1] = f.y;
        V[4 * m + 2] = f.z; V[4 * m + 3] = f.w;
    }
    float4 o;
    float* op = &o.x;
    #pragma unroll
    for (int j = 0; j < 4; j++) {
        float c0 = (DIR > 0) ? V[j]     : V[24 + j];
        float c1 = (DIR > 0) ? V[j + 1] : V[23 + j];
        float base = (c0 + c1) * (1.0f / 6.0f);
        float m = 1e30f;
        #pragma unroll
        for (int i = 0; i < ND; i++) {
            float ck = (DIR > 0) ? V[j + 2 + i] : V[22 + j - i];
            float v = fabsf(base + (float)(i + 1) - ck * (1.0f / 3.0f));
            m = fminf(m, v);
        }
        op[j] = fminf(m, 1.0f);  // m >= 0, so clip(0,1) == min(.,1)
    }
    ((float4*)orow)[t] = o;
}

__global__ __launch_bounds__(BT) void occl_kernel(const float* __restrict__ disp,
                                                  const float* __restrict__ bsl,
                                                  float* __restrict__ out) {
    // XCD swizzle: hardware assigns block g to XCD (g % 8). Remap so each XCD
    // owns a contiguous run of rows (here: exactly one batch) -> rows r-1/r/r+1
    // are re-read from the same XCD's L2 instead of HBM 3x.
    int g = blockIdx.x;
    int nb = gridDim.x;
    int id = (nb & 7) ? g : ((g & 7) * (nb >> 3) + (g >> 3));
    const int row = id % H;
    const int batch = id / H;
    const float bs = bsl[batch];
    float* __restrict__ orow = out + (size_t)(batch * H + row) * W;
    const int t = threadIdx.x;

    if (bs == 0.0f) {
        float4 z = {0.0f, 0.0f, 0.0f, 0.0f};
        ((float4*)orow)[t] = z;
        return;
    }

    __shared__ float Cbuf[W + 48];
    float* Cs = Cbuf + 24;  // valid indices -24 .. W+23; Cs is 16B-aligned

    const float* __restrict__ dbase = disp + (size_t)batch * H * W;
    const float* __restrict__ r0 = dbase + (size_t)max(row - 1, 0) * W;
    const float* __restrict__ r1 = dbase + (size_t)row * W;
    const float* __restrict__ r2 = dbase + (size_t)min(row + 1, H - 1) * W;

    // Coalesced float4 staging: 320 threads x 4 floats = 1280 columns.
    float4 a = ((const float4*)r0)[t];
    float4 b = ((const float4*)r1)[t];
    float4 c = ((const float4*)r2)[t];
    float4 s;
    s.x = a.x + b.x + c.x;
    s.y = a.y + b.y + c.y;
    s.z = a.z + b.z + c.z;
    s.w = a.w + b.w + c.w;
    ((float4*)Cs)[t] = s;

    // Edge-replicated pads (scalar re-loads hit L1).
    if (t < 24) {
        Cs[t - 24] = r0[0] + r1[0] + r2[0];
    } else if (t >= 32 && t < 56) {
        Cs[W + (t - 32)] = r0[W - 1] + r1[W - 1] + r2[W - 1];
    }
    __syncthreads();

    if (bs < 0.0f) compute4<1>(Cs, orow, t);
    else           compute4<-1>(Cs, orow, t);
}

extern "C" void kernel_launch(void* const* d_in, const int* in_sizes, int n_in,
                              void* d_out, int out_size, void* d_ws, size_t ws_size,
                              hipStream_t stream) {
    const float* disp = (const float*)d_in[0];
    const float* bsl  = (const float*)d_in[1];
    float* out        = (float*)d_out;
    const int n_batch = in_sizes[1];  // bsline: one entry per batch

    occl_kernel<<<dim3(n_batch * H), BT, 0, stream>>>(disp, bsl, out);
}

// Round 3
// 75.149 us; speedup vs baseline: 1.0383x; 1.0030x over previous
//
#include <hip/hip_runtime.h>

#define W  1280
#define H  384
#define ND 21     // MAXDISP
#define BT 320    // 4 columns per thread
#define R  4      // rows per block (H % R == 0)

// Per output column c (DIR=+1 == maskl, bs<0):
//   base = (C[c] + C[c+DIR]) / 6
//   mask = clip( min_i |base + (i+1) - C[c+DIR*(2+i)]/3| , 0, 1)
// C = 3-row column sum (rows edge-clamped; columns edge-clamped both ends,
// left clamp only ever used by DIR=-1, right only by DIR=+1).
// Strength-reduced: term(j,m) = B_j + Q[m], m = j..j+20, where
//   DIR>0: Q[m] = (m+1)  - V[m+2]/3,  B_j = (V[j]+V[j+1])/6   - j
//   DIR<0: Q[m] = (21-m) - V[m+2]/3,  B_j = (V[24+j]+V[23+j])/6 + j
template <int DIR>
__device__ __forceinline__ void compute_row(const float* __restrict__ Cs,
                                            float* __restrict__ orow, int t) {
    float V[28];
    const float4* p = (const float4*)(Cs + ((DIR > 0) ? 4 * t : 4 * t - 24));
    #pragma unroll
    for (int m = 0; m < 7; m++) {
        float4 f = p[m];
        V[4*m+0] = f.x; V[4*m+1] = f.y; V[4*m+2] = f.z; V[4*m+3] = f.w;
    }
    float Q[24];
    #pragma unroll
    for (int m = 0; m < 24; m++) {
        float k = (DIR > 0) ? (float)(m + 1) : (float)(21 - m);
        Q[m] = k - V[m + 2] * (1.0f / 3.0f);
    }
    float4 o; float* op = &o.x;
    #pragma unroll
    for (int j = 0; j < 4; j++) {
        float base = (DIR > 0) ? (V[j] + V[j+1]) * (1.0f / 6.0f)
                               : (V[24+j] + V[23+j]) * (1.0f / 6.0f);
        float B = (DIR > 0) ? (base - (float)j) : (base + (float)j);
        float m0 = 1e30f;
        #pragma unroll
        for (int i = 0; i < ND; i++)
            m0 = fminf(m0, fabsf(B + Q[j + i]));
        op[j] = fminf(m0, 1.0f);   // m0 >= 0, so clip(0,1) == min(.,1)
    }
    ((float4*)orow)[t] = o;
}

template <int DIR>
__device__ __forceinline__ void run_rows(const float* __restrict__ dbase,
                                         float* __restrict__ outb,
                                         float (*Cbuf)[W + 48],
                                         int rs, int t) {
    const bool lp = (t < 24);
    const bool rp = (t >= 32 && t < 56);
    const int  ecol = lp ? 0 : (W - 1);

    // Rolling registers: rows r-1, r, r+1 for current output row r.
    int r0 = max(rs - 1, 0);
    float4 a = ((const float4*)(dbase + (size_t)r0       * W))[t];
    float4 b = ((const float4*)(dbase + (size_t)rs       * W))[t];
    float4 c = ((const float4*)(dbase + (size_t)(rs + 1) * W))[t];
    float4 d = {0, 0, 0, 0};
    float ea = 0, eb = 0, ec = 0, ed = 0;
    if (lp || rp) {
        ea = dbase[(size_t)r0       * W + ecol];
        eb = dbase[(size_t)rs       * W + ecol];
        ec = dbase[(size_t)(rs + 1) * W + ecol];
    }

    #pragma unroll
    for (int r = 0; r < R; r++) {
        float* Cs = Cbuf[r & 1] + 24;
        float4 s;
        s.x = a.x + b.x + c.x; s.y = a.y + b.y + c.y;
        s.z = a.z + b.z + c.z; s.w = a.w + b.w + c.w;
        ((float4*)Cs)[t] = s;
        if (lp)      Cs[t - 24]      = ea + eb + ec;
        else if (rp) Cs[W + (t - 32)] = ea + eb + ec;

        // Prefetch next input row before the barrier.
        if (r + 1 < R) {
            int nr = min(rs + r + 2, H - 1);
            d = ((const float4*)(dbase + (size_t)nr * W))[t];
            if (lp || rp) ed = dbase[(size_t)nr * W + ecol];
        }
        __syncthreads();
        compute_row<DIR>(Cs, outb + (size_t)r * W, t);
        a = b; b = c; c = d;
        ea = eb; eb = ec; ec = ed;
    }
}

__global__ __launch_bounds__(BT) void occl_kernel(const float* __restrict__ disp,
                                                  const float* __restrict__ bsl,
                                                  float* __restrict__ out) {
    // XCD swizzle: HW maps block g -> XCD (g % 8). Remap so XCD k owns batch k
    // (96 consecutive row-blocks): its 1.97 MB input fits the per-XCD 4 MB L2,
    // so the 1.5x row re-reads hit L2, not HBM.
    int g = blockIdx.x, nb = gridDim.x;
    int id = (nb & 7) ? g : ((g & 7) * (nb >> 3) + (g >> 3));
    const int RB = H / R;
    const int batch = id / RB;
    const int rs = (id % RB) * R;
    const float bs = bsl[batch];
    const int t = threadIdx.x;
    float* outb = out + ((size_t)batch * H + rs) * W;

    if (bs == 0.0f) {
        float4 z = {0, 0, 0, 0};
        #pragma unroll
        for (int r = 0; r < R; r++) ((float4*)(outb + (size_t)r * W))[t] = z;
        return;
    }

    __shared__ float Cbuf[2][W + 48];   // double-buffered colsums, idx -24..W+23
    const float* dbase = disp + (size_t)batch * H * W;

    if (bs < 0.0f) run_rows<1>(dbase, outb, Cbuf, rs, t);
    else           run_rows<-1>(dbase, outb, Cbuf, rs, t);
}

extern "C" void kernel_launch(void* const* d_in, const int* in_sizes, int n_in,
                              void* d_out, int out_size, void* d_ws, size_t ws_size,
                              hipStream_t stream) {
    const float* disp = (const float*)d_in[0];
    const float* bsl  = (const float*)d_in[1];
    float* out        = (float*)d_out;
    const int n_batch = in_sizes[1];  // bsline: one entry per batch

    occl_kernel<<<dim3(n_batch * (H / R)), BT, 0, stream>>>(disp, bsl, out);
}